// Round 2
// baseline (1517.159 us; speedup 1.0000x reference)
//
#include <hip/hip_runtime.h>

#define TT 8192
#define BB 512
#define HH 16

typedef float vf2 __attribute__((ext_vector_type(2)));

__device__ __forceinline__ float rl(float v, int l) {
    return __uint_as_float(__builtin_amdgcn_readlane(__float_as_uint(v), l));
}

// Single-wave sequential GRU scan for batch element 511 only.
// Lane layout (wave 0):
//   lanes  0-15 : ALL THREE gate rows (r,z,n) of w_hh for unit i — no shuffles
//   lanes 16-20 : fc_w rows, stored in the r-gate register slots so the fc
//                 projection y_{t-1} = fc_w @ h_{t-1} + fc_b rides the r-chain
//                 instructions for free (pipelined 1 step behind)
// h_t is wave-uniform in SGPRs via 16 v_readlane per step (VALU-only; the
// previous version's two ds_swizzle shuffles were ~150 cyc of exposed LDS
// latency per step on a single wave).
__global__ __launch_bounds__(256, 1) void gru_scan_kernel(
    const float* __restrict__ x, const float* __restrict__ w_ih,
    const float* __restrict__ w_hh, const float* __restrict__ b_ih,
    const float* __restrict__ b_hh, const float* __restrict__ fc_w,
    const float* __restrict__ fc_b, float* __restrict__ out)
{
    __shared__ float xs[TT + 8];
    const int tid = threadIdx.x;
    // stage x[:,511,0] into LDS (one-time strided gather)
    #pragma unroll 4
    for (int i = tid; i < TT; i += 256) xs[i] = x[i * BB + (BB - 1)];
    if (tid < 8) xs[TT + tid] = 0.0f;   // pad for the t+1 prefetch read
    __syncthreads();
    if (tid >= 64) return;              // waves 1-3 retire
    const int lane = tid;

    // ---- per-lane constants ----
    vf2 wr[8], wz[8], wn[8];
    float cr = 0.f, cz = 0.f, cn = 0.f;   // chain inits (biases folded)
    float xmr = 0.f, xmz = 0.f;           // x coefficients for r/z (IN=1)
    float xa = 0.f, xc = 0.f;             // n-gate x-part: w_ih[32+i], b_ih[32+i]
    #pragma unroll
    for (int k = 0; k < 8; ++k) {
        wr[k] = vf2{0.f, 0.f}; wz[k] = vf2{0.f, 0.f}; wn[k] = vf2{0.f, 0.f};
    }
    if (lane < HH) {
        const vf2* r0 = (const vf2*)(w_hh + lane * HH);            // r row
        const vf2* r1 = (const vf2*)(w_hh + (HH + lane) * HH);     // z row
        const vf2* r2 = (const vf2*)(w_hh + (2 * HH + lane) * HH); // n row
        #pragma unroll
        for (int k = 0; k < 8; ++k) { wr[k] = r0[k]; wz[k] = r1[k]; wn[k] = r2[k]; }
        cr  = b_ih[lane] + b_hh[lane];
        cz  = b_ih[HH + lane] + b_hh[HH + lane];
        cn  = b_hh[2 * HH + lane];
        xmr = w_ih[lane];
        xmz = w_ih[HH + lane];
        xa  = w_ih[2 * HH + lane];
        xc  = b_ih[2 * HH + lane];
    } else if (lane < HH + 5) {
        const vf2* rf = (const vf2*)(fc_w + (lane - HH) * HH);
        #pragma unroll
        for (int k = 0; k < 8; ++k) wr[k] = rf[k];
        cr = fc_b[lane - HH];
    }

    // h state, wave-uniform (SGPR pairs feeding v_pk_fma_f32)
    vf2 sh2[8];
    #pragma unroll
    for (int k = 0; k < 8; ++k) sh2[k] = vf2{0.f, 0.f};

    float hv = 0.f;                       // lane i's own h element (lanes 0-15)
    float xt = xs[0];
    const bool isfc = (lane >= HH && lane < HH + 5);
    float* outp = out + (lane - HH);      // only dereferenced on fc lanes

    for (int t = 0; t < TT; ++t) {
        float xtn = xs[t + 1];            // next x, off critical path

        // ---- r gate (and fc projection on lanes 16-20): 2 packed chains ----
        vf2 ra = {__builtin_fmaf(xt, xmr, cr), 0.f};
        vf2 rb = {0.f, 0.f};
        #pragma unroll
        for (int k = 0; k < 4; ++k) {
            ra = __builtin_elementwise_fma(sh2[k],     wr[k],     ra);
            rb = __builtin_elementwise_fma(sh2[k + 4], wr[k + 4], rb);
        }
        vf2 rs = ra + rb;
        float accR = rs.x + rs.y;
        // sigmoid(r) — head of the serial chain, issue ASAP
        float sr = __builtin_amdgcn_rcpf(1.f + __expf(-accR));

        // ---- n hidden-gate dot (independent of sr, fills its latency) ----
        vf2 na = {cn, 0.f};
        vf2 nb = {0.f, 0.f};
        #pragma unroll
        for (int k = 0; k < 4; ++k) {
            na = __builtin_elementwise_fma(sh2[k],     wn[k],     na);
            nb = __builtin_elementwise_fma(sh2[k + 4], wn[k + 4], nb);
        }
        vf2 ns = na + nb;
        float accN = ns.x + ns.y;

        // ---- z gate ----
        vf2 za = {__builtin_fmaf(xt, xmz, cz), 0.f};
        vf2 zb = {0.f, 0.f};
        #pragma unroll
        for (int k = 0; k < 4; ++k) {
            za = __builtin_elementwise_fma(sh2[k],     wz[k],     za);
            zb = __builtin_elementwise_fma(sh2[k + 4], wz[k + 4], zb);
        }
        vf2 zs = za + zb;
        float accZ = zs.x + zs.y;
        float sz = __builtin_amdgcn_rcpf(1.f + __expf(-accZ));

        // n = tanh(xn + r*hg_n);  tanh(p) = 1 - 2/(exp(2p)+1)
        float xn = __builtin_fmaf(xt, xa, xc);
        float pn = __builtin_fmaf(sr, accN, xn);
        float e2 = __expf(pn + pn);
        float nv = __builtin_fmaf(-2.f, __builtin_amdgcn_rcpf(e2 + 1.f), 1.f);

        // h_new = n + z*(h - n)
        float hnew = __builtin_fmaf(sz, hv - nv, nv);
        hv = hnew;

        // broadcast h_t to SGPRs for next step (VALU readlanes, no LDS)
        #pragma unroll
        for (int k = 0; k < 8; ++k) {
            sh2[k].x = rl(hnew, 2 * k);
            sh2[k].y = rl(hnew, 2 * k + 1);
        }

        // fc lanes' r-chain result this step = fc_w @ h_{t-1} + fc_b = y_{t-1}
        if (t > 0 && isfc) outp[(t - 1) * 5] = accR;
        xt = xtn;
    }

    // epilogue: y_{T-1} from final h
    vf2 fa = {cr, 0.f}, fb = {0.f, 0.f};
    #pragma unroll
    for (int k = 0; k < 4; ++k) {
        fa = __builtin_elementwise_fma(sh2[k],     wr[k],     fa);
        fb = __builtin_elementwise_fma(sh2[k + 4], wr[k + 4], fb);
    }
    vf2 fs = fa + fb;
    if (isfc) outp[(TT - 1) * 5] = fs.x + fs.y;
}

extern "C" void kernel_launch(void* const* d_in, const int* in_sizes, int n_in,
                              void* d_out, int out_size, void* d_ws, size_t ws_size,
                              hipStream_t stream) {
    const float* x    = (const float*)d_in[0];
    const float* w_ih = (const float*)d_in[1];
    const float* w_hh = (const float*)d_in[2];
    const float* b_ih = (const float*)d_in[3];
    const float* b_hh = (const float*)d_in[4];
    const float* fc_w = (const float*)d_in[5];
    const float* fc_b = (const float*)d_in[6];
    float* out = (float*)d_out;
    gru_scan_kernel<<<dim3(1), dim3(256), 0, stream>>>(
        x, w_ih, w_hh, b_ih, b_hh, fc_w, fc_b, out);
}

// Round 3
// 1178.435 us; speedup vs baseline: 1.2874x; 1.2874x over previous
//
#include <hip/hip_runtime.h>

#define TT 8192
#define BB 512
#define HH 16

typedef float vf2 __attribute__((ext_vector_type(2)));

__device__ __forceinline__ float rl(float v, int l) {
    return __uint_as_float(__builtin_amdgcn_readlane(__float_as_uint(v), l));
}
__device__ __forceinline__ float fexp2(float v) { return __builtin_amdgcn_exp2f(v); }
__device__ __forceinline__ float frcp(float v)  { return __builtin_amdgcn_rcpf(v); }

// Single-wave GRU scan, batch element 511 only.
//   lanes  0-15 : all three gate rows (r,z,n) for unit i; weights pre-scaled by
//                 -log2e (r,z) / +2log2e (n) so sigmoid = rcp(1+exp2(acc)) and
//                 tanh(p) = 1 - 2*rcp(exp2(acc)+1) with no extra muls.
//   lanes 16-20 : fc_w rows in the r-slots (unscaled) -> accR = y_{t-1} free.
// Inner loop is PURE VALU: x block-prefetched into double-banked regs via
// ds_read one half ahead; y batched in double-banked regs, 8 global stores per
// half whose vmcnt waits are ~2000 cycles stale (no exposed store latency).
__global__ __launch_bounds__(256, 1) void gru_scan_kernel(
    const float* __restrict__ x, const float* __restrict__ w_ih,
    const float* __restrict__ w_hh, const float* __restrict__ b_ih,
    const float* __restrict__ b_hh, const float* __restrict__ fc_w,
    const float* __restrict__ fc_b, float* __restrict__ out)
{
    __shared__ float xs[TT + 32];
    const int tid = threadIdx.x;
    #pragma unroll 4
    for (int i = tid; i < TT; i += 256) xs[i] = x[i * BB + (BB - 1)];
    if (tid < 32) xs[TT + tid] = 0.0f;     // pad for tail prefetch
    __syncthreads();
    if (tid >= 64) return;                 // waves 1-3 retire
    const int lane = tid;
    const float L2E = 1.44269504088896340736f;

    vf2 wr[8], wz[8], wn[8];
    #pragma unroll
    for (int k = 0; k < 8; ++k) {
        wr[k] = vf2{0.f, 0.f}; wz[k] = vf2{0.f, 0.f}; wn[k] = vf2{0.f, 0.f};
    }
    float cr = 0.f, cz = 0.f, cn = 0.f, xmr = 0.f, xmz = 0.f, xa = 0.f, xc = 0.f;
    if (lane < HH) {
        const float* r0 = w_hh + lane * HH;
        const float* r1 = w_hh + (HH + lane) * HH;
        const float* r2 = w_hh + (2 * HH + lane) * HH;
        #pragma unroll
        for (int k = 0; k < 8; ++k) {
            wr[k] = vf2{-L2E * r0[2*k], -L2E * r0[2*k+1]};
            wz[k] = vf2{-L2E * r1[2*k], -L2E * r1[2*k+1]};
            wn[k] = vf2{2.f*L2E * r2[2*k], 2.f*L2E * r2[2*k+1]};
        }
        cr  = -L2E * (b_ih[lane] + b_hh[lane]);
        cz  = -L2E * (b_ih[HH + lane] + b_hh[HH + lane]);
        cn  = 2.f*L2E * b_hh[2*HH + lane];
        xmr = -L2E * w_ih[lane];
        xmz = -L2E * w_ih[HH + lane];
        xa  = 2.f*L2E * w_ih[2*HH + lane];
        xc  = 2.f*L2E * b_ih[2*HH + lane];
    } else if (lane < HH + 5) {
        const float* rf = fc_w + (lane - HH) * HH;
        #pragma unroll
        for (int k = 0; k < 8; ++k) wr[k] = vf2{rf[2*k], rf[2*k+1]};
        cr = fc_b[lane - HH];
    }
    const vf2 crp = {cr, 0.f}, czp = {cz, 0.f}, cnp = {cn, 0.f};

    vf2 sh[8];
    #pragma unroll
    for (int k = 0; k < 8; ++k) sh[k] = vf2{0.f, 0.f};
    float hv = 0.f;

    const bool isfc = (lane >= HH && lane < HH + 5);
    const int  jfc  = lane - HH;

    auto step = [&](float xt) -> float {
        // r chain (fc projection on lanes 16-20)
        vf2 ra = __builtin_elementwise_fma(sh[0], wr[0], crp);
        ra = __builtin_elementwise_fma(sh[1], wr[1], ra);
        ra = __builtin_elementwise_fma(sh[2], wr[2], ra);
        ra = __builtin_elementwise_fma(sh[3], wr[3], ra);
        vf2 rb = sh[4] * wr[4];
        rb = __builtin_elementwise_fma(sh[5], wr[5], rb);
        rb = __builtin_elementwise_fma(sh[6], wr[6], rb);
        rb = __builtin_elementwise_fma(sh[7], wr[7], rb);
        vf2 rs = ra + rb;
        float accR = __builtin_fmaf(xt, xmr, rs.x + rs.y);
        float sr = frcp(1.f + fexp2(accR));          // sigmoid(r), scaled exp2
        // n hidden chain (independent of sr)
        vf2 na = __builtin_elementwise_fma(sh[0], wn[0], cnp);
        na = __builtin_elementwise_fma(sh[1], wn[1], na);
        na = __builtin_elementwise_fma(sh[2], wn[2], na);
        na = __builtin_elementwise_fma(sh[3], wn[3], na);
        vf2 nb = sh[4] * wn[4];
        nb = __builtin_elementwise_fma(sh[5], wn[5], nb);
        nb = __builtin_elementwise_fma(sh[6], wn[6], nb);
        nb = __builtin_elementwise_fma(sh[7], wn[7], nb);
        vf2 ns = na + nb;
        float accN = ns.x + ns.y;                     // scaled by 2*log2e
        // z chain
        vf2 za = __builtin_elementwise_fma(sh[0], wz[0], czp);
        za = __builtin_elementwise_fma(sh[1], wz[1], za);
        za = __builtin_elementwise_fma(sh[2], wz[2], za);
        za = __builtin_elementwise_fma(sh[3], wz[3], za);
        vf2 zb = sh[4] * wz[4];
        zb = __builtin_elementwise_fma(sh[5], wz[5], zb);
        zb = __builtin_elementwise_fma(sh[6], wz[6], zb);
        zb = __builtin_elementwise_fma(sh[7], wz[7], zb);
        vf2 zv = za + zb;
        float accZ = __builtin_fmaf(xt, xmz, zv.x + zv.y);
        float sz = frcp(1.f + fexp2(accZ));
        // n = tanh ; h' = n + z*(h-n)
        float xn = __builtin_fmaf(xt, xa, xc);
        float pn = __builtin_fmaf(sr, accN, xn);      // = 2*log2e * p
        float nv = __builtin_fmaf(-2.f, frcp(fexp2(pn) + 1.f), 1.f);
        float hnew = __builtin_fmaf(sz, hv - nv, nv);
        hv = hnew;
        #pragma unroll
        for (int k = 0; k < 8; ++k) {
            sh[k].x = rl(hnew, 2 * k);
            sh[k].y = rl(hnew, 2 * k + 1);
        }
        return accR;
    };

    float xb[2][8], yb[2][8];

#define HALF(B, TB, S0) do {                                                   \
        _Pragma("unroll")                                                      \
        for (int i = 0; i < 8; ++i) xb[(B) ^ 1][i] = xs[(TB) + 8 + i];         \
        _Pragma("unroll")                                                      \
        for (int s = 0; s < 8; ++s) yb[B][s] = step(xb[B][s]);                 \
        if (isfc) {                                                            \
            _Pragma("unroll")                                                  \
            for (int s = (S0); s < 8; ++s)                                     \
                out[((TB) + s - 1) * 5 + jfc] = yb[B][s];                      \
        }                                                                      \
    } while (0)

    #pragma unroll
    for (int i = 0; i < 8; ++i) xb[0][i] = xs[i];
    HALF(0, 0, 1);          // y_{-1} slot skipped
    HALF(1, 8, 0);
    int tb = 16;
    for (int kk = 0; kk < 510; ++kk) {
        HALF(0, tb, 0);
        HALF(1, tb + 8, 0);
        tb += 16;
    }
    HALF(0, tb, 0);         // tb = 8176
    HALF(1, tb + 8, 0);     // tb = 8184 -> prefetch reads pad, steps t..8191
#undef HALF

    // epilogue: y_{T-1} from final h (r-slot weights = fc rows on fc lanes)
    vf2 fa = __builtin_elementwise_fma(sh[0], wr[0], crp);
    fa = __builtin_elementwise_fma(sh[1], wr[1], fa);
    fa = __builtin_elementwise_fma(sh[2], wr[2], fa);
    fa = __builtin_elementwise_fma(sh[3], wr[3], fa);
    vf2 fb = sh[4] * wr[4];
    fb = __builtin_elementwise_fma(sh[5], wr[5], fb);
    fb = __builtin_elementwise_fma(sh[6], wr[6], fb);
    fb = __builtin_elementwise_fma(sh[7], wr[7], fb);
    vf2 fs = fa + fb;
    if (isfc) out[(TT - 1) * 5 + jfc] = fs.x + fs.y;
}

extern "C" void kernel_launch(void* const* d_in, const int* in_sizes, int n_in,
                              void* d_out, int out_size, void* d_ws, size_t ws_size,
                              hipStream_t stream) {
    const float* x    = (const float*)d_in[0];
    const float* w_ih = (const float*)d_in[1];
    const float* w_hh = (const float*)d_in[2];
    const float* b_ih = (const float*)d_in[3];
    const float* b_hh = (const float*)d_in[4];
    const float* fc_w = (const float*)d_in[5];
    const float* fc_b = (const float*)d_in[6];
    float* out = (float*)d_out;
    gru_scan_kernel<<<dim3(1), dim3(256), 0, stream>>>(
        x, w_ih, w_hh, b_ih, b_hh, fc_w, fc_b, out);
}